// Round 9
// baseline (599.769 us; speedup 1.0000x reference)
//
#include <hip/hip_runtime.h>
#include <hip/hip_bf16.h>
#include <math.h>

typedef __attribute__((ext_vector_type(8))) short short8;   // 8 x bf16 (MFMA frag)
typedef __attribute__((ext_vector_type(4))) float floatx4;  // MFMA accumulator

__device__ __forceinline__ ushort f2bf(float f) {
  __hip_bfloat16 h = __float2bfloat16(f);
  return *reinterpret_cast<ushort*>(&h);
}
__device__ __forceinline__ float bf2f(ushort u) {
  union { unsigned int i; float f; } c; c.i = ((unsigned)u) << 16; return c.f;
}

// async global->LDS 16B DMA (dest = wave-uniform base + lane*16)
__device__ __forceinline__ void lds_dma16(const void* g, void* l) {
  __builtin_amdgcn_global_load_lds((const __attribute__((address_space(1))) void*)g,
                                   (__attribute__((address_space(3))) void*)l, 16, 0, 0);
}

// ---------- fused fp32 -> bf16 conversion for all four weights ----------
__global__ __launch_bounds__(256) void cvt_all(const float* __restrict__ p0, ushort* __restrict__ o0, int b0,
                                               const float* __restrict__ p1, ushort* __restrict__ o1, int b1,
                                               const float* __restrict__ p2, ushort* __restrict__ o2, int b2,
                                               const float* __restrict__ p3, ushort* __restrict__ o3) {
  int b = blockIdx.x;
  const float* in; ushort* out; int base;
  if (b < b0)            { in = p0; out = o0; base = 0; }
  else if (b < b0 + b1)  { in = p1; out = o1; base = b0; }
  else if (b < b0 + b1 + b2) { in = p2; out = o2; base = b0 + b1; }
  else                   { in = p3; out = o3; base = b0 + b1 + b2; }
  int i = (b - base) * 256 + threadIdx.x;
  float4 v = ((const float4*)in)[i];
  ushort4 o;
  o.x = f2bf(v.x); o.y = f2bf(v.y); o.z = f2bf(v.z); o.w = f2bf(v.w);
  ((ushort4*)out)[i] = o;
}

// ---------- RMSNorm fp32 -> bf16 ----------
__global__ __launch_bounds__(256) void rmsnorm_f32(const float* __restrict__ x,
                                                   const float* __restrict__ gamma,
                                                   ushort* __restrict__ y, int D, float sqrtD) {
  const int row = blockIdx.x;
  const float* xr = x + (size_t)row * D;
  float ss = 0.f;
  for (int i = threadIdx.x * 4; i < D; i += 1024) {
    float4 v = *(const float4*)&xr[i];
    ss += v.x * v.x + v.y * v.y + v.z * v.z + v.w * v.w;
  }
#pragma unroll
  for (int off = 1; off < 64; off <<= 1) ss += __shfl_xor(ss, off);
  __shared__ float red[4];
  if ((threadIdx.x & 63) == 0) red[threadIdx.x >> 6] = ss;
  __syncthreads();
  ss = red[0] + red[1] + red[2] + red[3];
  const float sc = sqrtD / fmaxf(sqrtf(ss), 1e-12f);
  for (int i = threadIdx.x * 4; i < D; i += 1024) {
    float4 v = *(const float4*)&xr[i];
    ushort4 o;
    o.x = f2bf(v.x * sc * gamma[i]);
    o.y = f2bf(v.y * sc * gamma[i + 1]);
    o.z = f2bf(v.z * sc * gamma[i + 2]);
    o.w = f2bf(v.w * sc * gamma[i + 3]);
    *(ushort4*)&y[(size_t)row * D + i] = o;
  }
}

// ---------- RMSNorm bf16 -> bf16, single-pass (row held in registers) ----------
__global__ __launch_bounds__(256) void rmsnorm_bf16(const ushort* __restrict__ x,
                                                    const float* __restrict__ gamma,
                                                    ushort* __restrict__ y, int D, float sqrtD) {
  const int row = blockIdx.x;
  const ushort* xr = x + (size_t)row * D;
  short8 v[8];
  float ss = 0.f;
#pragma unroll
  for (int j = 0; j < 8; j++) {
    v[j] = *(const short8*)&xr[threadIdx.x * 8 + j * 2048];
#pragma unroll
    for (int e = 0; e < 8; e++) { float f = bf2f((ushort)v[j][e]); ss += f * f; }
  }
#pragma unroll
  for (int off = 1; off < 64; off <<= 1) ss += __shfl_xor(ss, off);
  __shared__ float red[4];
  if ((threadIdx.x & 63) == 0) red[threadIdx.x >> 6] = ss;
  __syncthreads();
  ss = red[0] + red[1] + red[2] + red[3];
  const float sc = sqrtD / fmaxf(sqrtf(ss), 1e-12f);
#pragma unroll
  for (int j = 0; j < 8; j++) {
    const int i = threadIdx.x * 8 + j * 2048;
    short8 ov;
#pragma unroll
    for (int e = 0; e < 8; e++) ov[e] = (short)f2bf(bf2f((ushort)v[j][e]) * sc * gamma[i + e]);
    *(short8*)&y[(size_t)row * D + i] = ov;
  }
}

// ---------- GEMM v4 (R5-proven): 128x128 tile, BK=64, single-buffer, XOR swizzle ----------
template <int EPI, int ACT, int OUTBF16>
__global__ __launch_bounds__(256, 3) void gemm3(const ushort* __restrict__ A,
                                                const ushort* __restrict__ B,
                                                const float* __restrict__ bias,
                                                const float* __restrict__ bias2,
                                                void* __restrict__ C1,
                                                void* __restrict__ C2,
                                                int M, int N, int K, int Ksplit, float scale) {
  __shared__ ushort As[128 * 64];
  __shared__ ushort Bs[128 * 64];
  const int tid = threadIdx.x;
  const int wave = tid >> 6;
  const int lane = tid & 63;
  const int c16 = lane & 15;
  const int quad = lane >> 4;
  const int wm = wave >> 1;
  const int wn = wave & 1;
  // --- XCD swizzle (bijective per z-plane; plane sizes are multiples of 8) ---
  const int P = gridDim.x * gridDim.y;
  const int lin = blockIdx.x + gridDim.x * blockIdx.y;
  const int lin2 = (lin & 7) * (P >> 3) + (lin >> 3);
  const int bx = lin2 & 7;              // gridDim.x == 8 at every call site
  const int by = lin2 >> 3;
  const size_t m0 = (size_t)bx * 128;
  const size_t n0 = (size_t)by * 128;
  const int kbeg = blockIdx.z * Ksplit;
  const int kend = kbeg + Ksplit;

  const int rsub = lane >> 3;
  const int csw = (lane & 7) ^ rsub;

  const floatx4 zero = {0.f, 0.f, 0.f, 0.f};
  floatx4 acc[4][4];
#pragma unroll
  for (int a = 0; a < 4; a++)
#pragma unroll
    for (int b = 0; b < 4; b++) acc[a][b] = zero;

  for (int k0 = kbeg; k0 < kend; k0 += 64) {
    __syncthreads();
#pragma unroll
    for (int i = 0; i < 4; i++) {
      const int j = wave * 4 + i;
      const int r = j * 8 + rsub;
      lds_dma16(&A[(m0 + r) * K + k0 + csw * 8], (void*)(As + j * 512));
      lds_dma16(&B[(n0 + r) * K + k0 + csw * 8], (void*)(Bs + j * 512));
    }
    __syncthreads();
#pragma unroll
    for (int kc = 0; kc < 2; kc++) {
      short8 af[4], bf4[4];
#pragma unroll
      for (int mt = 0; mt < 4; mt++) {
        const int row = wm * 64 + mt * 16 + c16;
        af[mt] = *(const short8*)&As[row * 64 + (((kc * 4 + quad) ^ (row & 7)) << 3)];
      }
#pragma unroll
      for (int nt = 0; nt < 4; nt++) {
        const int row = wn * 64 + nt * 16 + c16;
        bf4[nt] = *(const short8*)&Bs[row * 64 + (((kc * 4 + quad) ^ (row & 7)) << 3)];
      }
#pragma unroll
      for (int mt = 0; mt < 4; mt++)
#pragma unroll
        for (int nt = 0; nt < 4; nt++)
          acc[mt][nt] = __builtin_amdgcn_mfma_f32_16x16x32_bf16(af[mt], bf4[nt], acc[mt][nt], 0, 0, 0);
    }
  }

#pragma unroll
  for (int mt = 0; mt < 4; mt++) {
#pragma unroll
    for (int nt = 0; nt < 4; nt++) {
      const size_t col = n0 + wn * 64 + nt * 16 + c16;
      const size_t row0 = m0 + wm * 64 + mt * 16 + quad * 4;
      if (EPI == 0) {
        const float bv = bias[col];
#pragma unroll
        for (int r = 0; r < 4; r++) {
          float v = acc[mt][nt][r] + bv;
          if (ACT) v = v / (1.f + __expf(-v));
          if (OUTBF16) ((ushort*)C1)[(row0 + r) * N + col] = f2bf(v);
          else         ((float*)C1)[(row0 + r) * N + col] = v;
        }
      } else if (EPI == 1) {
        float* plane = (float*)C1 + (size_t)blockIdx.z * M * N;
#pragma unroll
        for (int r = 0; r < 4; r++)
          plane[(row0 + r) * N + col] = acc[mt][nt][r];
      } else {
        if (col < 16384) {
          const float bv = bias[col];
#pragma unroll
          for (int r = 0; r < 4; r++)
            ((ushort*)C1)[(row0 + r) * 16384 + col] = f2bf((acc[mt][nt][r] + bv) * scale);
        } else {
          const size_t ckv = col - 16384;
          const float bv = bias2[ckv];
#pragma unroll
          for (int r = 0; r < 4; r++)
            ((ushort*)C2)[(row0 + r) * 2048 + ckv] = f2bf(acc[mt][nt][r] + bv);
        }
      }
    }
  }
}

// ---------- GEMM 8-phase 256x256 (T2+T3+T4+T5; m201 template), plane epilogue ----------
// 512 thr = 8 waves (2M x 4N), per-wave out 128x64, BK=64, LDS 128 KiB (A/B dbuf).
// Per K-tile: 4 phases, each {stage 1 half-tile of kt+1 (2 gload_lds/thr), barrier,
// ds_read frags, 16 MFMA, barrier}. vmcnt(2) only at K-tile boundary: next tile's
// first half-tile stays in flight through the whole K-tile (T4). Race audit: reads
// of buf all complete before phase-3 barrier of its K-tile; buf^1 staging starts
// after that barrier; per-phase barriers add ordering only.
#define GP8_COMPUTE_PAIR(Q)                                                          \
  {                                                                                  \
    __builtin_amdgcn_s_setprio(1);                                                   \
    _Pragma("unroll")                                                                \
    for (int m2 = 0; m2 < 2; m2++) {                                                 \
      const int mt = (Q) * 2 + m2;                                                   \
      const int row = wm * 128 + mt * 16 + c16;                                      \
      _Pragma("unroll")                                                              \
      for (int kc = 0; kc < 2; kc++) {                                               \
        short8 af = *(const short8*)&Al[buf][row * 64 + (((kc * 4 + quad) ^ (row & 7)) << 3)]; \
        _Pragma("unroll")                                                            \
        for (int nt = 0; nt < 4; nt++)                                               \
          acc[(Q) * 2 + m2][nt] =                                                    \
              __builtin_amdgcn_mfma_f32_16x16x32_bf16(af, bf[nt][kc], acc[(Q) * 2 + m2][nt], 0, 0, 0); \
      }                                                                              \
    }                                                                                \
    __builtin_amdgcn_s_setprio(0);                                                   \
  }

__global__ __launch_bounds__(512, 2) void gemm8p(const ushort* __restrict__ A,
                                                 const ushort* __restrict__ B,
                                                 float* __restrict__ planes,
                                                 int M, int N, int K, int Ksplit) {
  __shared__ ushort Al[2][256 * 64];   // 64 KiB
  __shared__ ushort Bl[2][256 * 64];   // 64 KiB
  const int tid = threadIdx.x;
  const int w = tid >> 6;              // 0..7
  const int lane = tid & 63;
  const int c16 = lane & 15;
  const int quad = lane >> 4;
  const int wm = w >> 2;               // 0..1 (M half)
  const int wn = w & 3;                // 0..3 (N quarter)
  const int rsub = lane >> 3;
  const int csw = (lane & 7) ^ rsub;

  // XCD swizzle: P=32 spatial tiles, 8 z-planes (32*z % 8 == 0 keeps parity).
  // XCD x owns lin2 in [4x,4x+4) -> one 256-col B panel per XCD.
  const int P = gridDim.x * gridDim.y;
  const int lin = blockIdx.x + gridDim.x * blockIdx.y;
  const int lin2 = (lin & 7) * (P >> 3) + (lin >> 3);
  const size_t m0 = (size_t)(lin2 & 3) * 256;
  const size_t n0 = (size_t)(lin2 >> 2) * 256;
  const int kbeg = blockIdx.z * Ksplit;
  const int nkt = Ksplit >> 6;

  const floatx4 zero = {0.f, 0.f, 0.f, 0.f};
  floatx4 acc[8][4];
#pragma unroll
  for (int a = 0; a < 8; a++)
#pragma unroll
    for (int b = 0; b < 4; b++) acc[a][b] = zero;

  // stage one 128-row half-tile (16 KiB): 2 x gload_lds per thread, XOR chunk swizzle
  auto stageA = [&](int bu, int h, int k0) {
#pragma unroll
    for (int i = 0; i < 2; i++) {
      const int j = w * 2 + i;                 // 0..15
      const int r = h * 128 + j * 8 + rsub;
      lds_dma16(&A[(m0 + r) * K + k0 + csw * 8], (void*)(&Al[bu][h * 8192 + j * 512]));
    }
  };
  auto stageB = [&](int bu, int h, int k0) {
#pragma unroll
    for (int i = 0; i < 2; i++) {
      const int j = w * 2 + i;
      const int r = h * 128 + j * 8 + rsub;
      lds_dma16(&B[(n0 + r) * K + k0 + csw * 8], (void*)(&Bl[bu][h * 8192 + j * 512]));
    }
  };

  // prologue: all 4 half-tiles of K-tile 0 (8 loads/thread outstanding)
  stageA(0, 0, kbeg); stageB(0, 0, kbeg); stageA(0, 1, kbeg); stageB(0, 1, kbeg);

  short8 bf[4][2];

  for (int kt = 0; kt < nkt; kt++) {
    const int buf = kt & 1;
    const int kn = kbeg + (kt + 1) * 64;
    const bool more = (kt + 1 < nkt);

    // ---- phase 0: stage A-h0(kt+1); retire kt's 8 loads, keep the 2 new in flight ----
    if (more) {
      stageA(buf ^ 1, 0, kn);
      asm volatile("s_waitcnt vmcnt(2) lgkmcnt(0)\n\ts_barrier" ::: "memory");
    } else {
      asm volatile("s_waitcnt vmcnt(0) lgkmcnt(0)\n\ts_barrier" ::: "memory");
    }
#pragma unroll
    for (int nt = 0; nt < 4; nt++)
#pragma unroll
      for (int kc = 0; kc < 2; kc++) {
        const int row = wn * 64 + nt * 16 + c16;
        bf[nt][kc] = *(const short8*)&Bl[buf][row * 64 + (((kc * 4 + quad) ^ (row & 7)) << 3)];
      }
    GP8_COMPUTE_PAIR(0)
    asm volatile("s_barrier" ::: "memory");

    // ---- phase 1: stage B-h0(kt+1) ----
    if (more) stageB(buf ^ 1, 0, kn);
    asm volatile("s_barrier" ::: "memory");
    GP8_COMPUTE_PAIR(1)
    asm volatile("s_barrier" ::: "memory");

    // ---- phase 2: stage A-h1(kt+1) ----
    if (more) stageA(buf ^ 1, 1, kn);
    asm volatile("s_barrier" ::: "memory");
    GP8_COMPUTE_PAIR(2)
    asm volatile("s_barrier" ::: "memory");

    // ---- phase 3: stage B-h1(kt+1) ----
    if (more) stageB(buf ^ 1, 1, kn);
    asm volatile("s_barrier" ::: "memory");
    GP8_COMPUTE_PAIR(3)
    asm volatile("s_barrier" ::: "memory");
  }

  // epilogue: fp32 plane write (split-K partial)
  float* plane = planes + (size_t)blockIdx.z * M * N;
#pragma unroll
  for (int mt = 0; mt < 8; mt++) {
#pragma unroll
    for (int nt = 0; nt < 4; nt++) {
      const size_t col = n0 + wn * 64 + nt * 16 + c16;
      const size_t row0 = m0 + wm * 128 + mt * 16 + quad * 4;
#pragma unroll
      for (int r = 0; r < 4; r++)
        plane[(row0 + r) * N + col] = acc[mt][nt][r];
    }
  }
}

// ---------- split-K reduce + bias + SiLU epilogue ----------
template <int NZ, int OUTBF16>
__global__ __launch_bounds__(256) void epi_sum_silu(const float* __restrict__ accb,
                                                    const float* __restrict__ bias,
                                                    void* __restrict__ outp, int N, int n4,
                                                    size_t plane4) {
  int i = blockIdx.x * 256 + threadIdx.x;
  if (i >= n4) return;
  float4 v = ((const float4*)accb)[i];
#pragma unroll
  for (int z = 1; z < NZ; z++) {
    float4 p = ((const float4*)accb)[i + z * plane4];
    v.x += p.x; v.y += p.y; v.z += p.z; v.w += p.w;
  }
  const float4 b = *(const float4*)&bias[(i * 4) % N];
  v.x += b.x; v.y += b.y; v.z += b.z; v.w += b.w;
  v.x = v.x / (1.f + __expf(-v.x));
  v.y = v.y / (1.f + __expf(-v.y));
  v.z = v.z / (1.f + __expf(-v.z));
  v.w = v.w / (1.f + __expf(-v.w));
  if (OUTBF16) {
    ushort4 o; o.x = f2bf(v.x); o.y = f2bf(v.y); o.z = f2bf(v.z); o.w = f2bf(v.w);
    ((ushort4*)outp)[i] = o;
  } else {
    ((float4*)outp)[i] = v;
  }
}

// ---------- V transpose: KV(S,2048) -> VT(G,128,S) ----------
__global__ __launch_bounds__(256) void vtrans(const ushort* __restrict__ KV,
                                              ushort* __restrict__ VT) {
  __shared__ ushort Vl[64 * 138];
  const int tid = threadIdx.x;
  const int t0 = blockIdx.x * 64;
  const int g = blockIdx.y;
#pragma unroll
  for (int i = 0; i < 16; i++) {
    int idx = tid + i * 256;
    int r = idx >> 6, dc = idx & 63;
    *(uint*)&Vl[r * 138 + dc * 2] =
        *(const uint*)&KV[(size_t)(t0 + r) * 2048 + 1024 + g * 128 + dc * 2];
  }
  __syncthreads();
#pragma unroll
  for (int i = 0; i < 4; i++) {
    int idx = tid + i * 256;
    int dv = idx >> 3, tch = idx & 7;
    short8 o;
#pragma unroll
    for (int j = 0; j < 8; j++) o[j] = (short)Vl[(tch * 8 + j) * 138 + dv];
    *(short8*)&VT[(size_t)g * 131072 + (size_t)dv * 1024 + t0 + tch * 8] = o;
  }
}

// ---------- Flash attention v9 (R5-proven): slim waves for 2 blocks/CU ----------
__global__ __launch_bounds__(512, 4) void attn9(const ushort* __restrict__ Q,
                                                const ushort* __restrict__ KV,
                                                const ushort* __restrict__ VT,
                                                ushort* __restrict__ Z) {
  __shared__ ushort Kl[2][64 * 128];   // [T][dq] unpadded, XOR chunk swizzle
  __shared__ ushort Vt[128 * 64];      // [dv][T] unpadded, XOR chunk swizzle (single buf)
  __shared__ ushort Pl[128 * 64];      // [row][T] ld=64, XOR chunk swizzle
  float* Ls = (float*)Pl;              // [128] aliased; valid after last PV
  const int tid = threadIdx.x;
  const int w = tid >> 6;              // 0..7
  const int lane = tid & 63;
  const int c16 = lane & 15;
  const int quad = lane >> 4;
  const int b = (blockIdx.x & 7) * 128 + (blockIdx.x >> 3);
  const int hh = b >> 3;               // head 0..127
  const int qb = b & 7;                // 128-row chunk of S=1024
  const int g = hh >> 4;
  const int prow0 = (w & 3) * 32;      // PV rows (block-local)
  const int dv0 = (w >> 2) * 64;       // PV dv half

  const ushort* Kg = KV + (size_t)g * 128;
  const ushort* Vg = VT + (size_t)g * 131072;

  short8 aq[4];
#pragma unroll
  for (int kc = 0; kc < 4; kc++)
    aq[kc] = *(const short8*)&Q[(size_t)(qb * 128 + w * 16 + c16) * 16384 +
                                hh * 128 + kc * 32 + quad * 8];

  const floatx4 zero = {0.f, 0.f, 0.f, 0.f};
  floatx4 o[2][4];
  float lacc[4];
#pragma unroll
  for (int mt = 0; mt < 2; mt++)
#pragma unroll
    for (int nt = 0; nt < 4; nt++) o[mt][nt] = zero;
#pragma unroll
  for (int r = 0; r < 4; r++) lacc[r] = 0.f;

  const int kr16 = lane >> 4;
  const int kc16 = lane & 15;
  const int vr8 = lane >> 3;
  const int vc8 = lane & 7;

  auto stageK = [&](int buf, int t0) {
#pragma unroll
    for (int i = 0; i < 2; i++) {
      int krow = w * 8 + i * 4 + kr16;
      int kcs = kc16 ^ (krow & 7);
      lds_dma16(&Kg[(size_t)(t0 + krow) * 2048 + kcs * 8],
                (void*)(&Kl[buf][w * 1024 + i * 512]));
    }
  };
  auto stageV = [&](int t0) {
#pragma unroll
    for (int i = 0; i < 2; i++) {
      int vrow = w * 16 + i * 8 + vr8;
      int vcs = vc8 ^ (vrow & 7);
      lds_dma16(&Vg[(size_t)vrow * 1024 + t0 + vcs * 8],
                (void*)(&Vt[w * 1024 + i * 512]));
    }
  };

  stageK(0, 0);

  for (int t = 0; t < 16; t++) {
    const int p = t & 1;
    __syncthreads();                    // K(t) staged; Vt, Pl free
    if (t < 15) stageK(p ^ 1, (t + 1) * 64);
    stageV(t * 64);

#pragma unroll
    for (int st = 0; st < 4; st++) {
      floatx4 s0 = zero;
      const int krow = st * 16 + c16;
      __builtin_amdgcn_s_setprio(1);
#pragma unroll
      for (int kc = 0; kc < 4; kc++) {
        short8 bk = *(const short8*)&Kl[p][krow * 128 + (((kc * 4 + quad) ^ (c16 & 7)) << 3)];
        s0 = __builtin_amdgcn_mfma_f32_16x16x32_bf16(aq[kc], bk, s0, 0, 0, 0);
      }
      __builtin_amdgcn_s_setprio(0);
#pragma unroll
      for (int r = 0; r < 4; r++) {
        float p0 = __expf(s0[r]);
        lacc[r] += p0;
        const int rlo = w * 16 + quad * 4 + r;
        const int sw = ((((st * 2) + (c16 >> 3)) ^ (rlo & 7)) << 3) | (c16 & 7);
        Pl[rlo * 64 + sw] = f2bf(p0);
      }
    }
    __syncthreads();                    // P visible; V(t) + K(t+1) DMA drained

#pragma unroll
    for (int tc = 0; tc < 2; tc++) {
      short8 ap[2];
#pragma unroll
      for (int mt = 0; mt < 2; mt++) {
        const int row = prow0 + mt * 16 + c16;
        ap[mt] = *(const short8*)&Pl[row * 64 + (((tc * 4 + quad) ^ (c16 & 7)) << 3)];
      }
      __builtin_amdgcn_s_setprio(1);
#pragma unroll
      for (int nt = 0; nt < 4; nt++) {
        const int dv = dv0 + nt * 16 + c16;
        short8 bv = *(const short8*)&Vt[dv * 64 + (((tc * 4 + quad) ^ (c16 & 7)) << 3)];
#pragma unroll
        for (int mt = 0; mt < 2; mt++)
          o[mt][nt] = __builtin_amdgcn_mfma_f32_16x16x32_bf16(ap[mt], bv, o[mt][nt], 0, 0, 0);
      }
      __builtin_amdgcn_s_setprio(0);
    }
  }

  __syncthreads();
#pragma unroll
  for (int r = 0; r < 4; r++) {
    float l = lacc[r];
    l += __shfl_xor(l, 1);
    l += __shfl_xor(l, 2);
    l += __shfl_xor(l, 4);
    l += __shfl_xor(l, 8);
    if (c16 == 0) Ls[w * 16 + quad * 4 + r] = l;
  }
  __syncthreads();

#pragma unroll
  for (int mt = 0; mt < 2; mt++) {
#pragma unroll
    for (int r = 0; r < 4; r++) {
      const float inv = 1.f / Ls[prow0 + mt * 16 + quad * 4 + r];
      const size_t row = (size_t)qb * 128 + prow0 + mt * 16 + quad * 4 + r;
#pragma unroll
      for (int nt = 0; nt < 4; nt++)
        Z[row * 16384 + hh * 128 + dv0 + nt * 16 + c16] = f2bf(o[mt][nt][r] * inv);
    }
  }
}

// ---------- host ----------
extern "C" void kernel_launch(void* const* d_in, const int* in_sizes, int n_in,
                              void* d_out, int out_size, void* d_ws, size_t ws_size,
                              hipStream_t stream) {
  (void)in_sizes; (void)n_in; (void)out_size;
  const float* x        = (const float*)d_in[0];
  const float* gamma_in = (const float*)d_in[1];
  const float* Wq_w     = (const float*)d_in[2];
  const float* Wq_b     = (const float*)d_in[3];
  const float* Wkv_w    = (const float*)d_in[4];
  const float* Wkv_b    = (const float*)d_in[5];
  const float* gamma_z  = (const float*)d_in[6];
  const float* W1       = (const float*)d_in[7];
  const float* b1       = (const float*)d_in[8];
  const float* W2       = (const float*)d_in[9];
  const float* b2       = (const float*)d_in[10];
  float* out = (float*)d_out;

  const size_t MB = 1024 * 1024;
  char* ws = (char*)d_ws;
  // big layout (174 MB, proven in R6) enables W1 8-phase split-K=8; else R5 path.
  const bool big = ws_size >= 174 * MB;

  ushort *xn, *Wqb, *Wkvb, *W1b, *W2b, *Qb, *KVb, *Zb, *VTb, *ZN, *H1;
  float *h1f, *outf;
  size_t off = 0;
  auto alloc = [&](size_t bytes) {
    void* p = ws + off;
    off += (bytes + 255) & ~(size_t)255;
    return p;
  };
  if (big) {
    // layout: xn | W1b | W2b | Qb | KVb | Wqb+Wkvb | Zb   (= 174 MB)
    xn   = (ushort*)alloc(2 * MB);
    W1b  = (ushort*)alloc(64 * MB);
    W2b  = (ushort*)alloc(4 * MB);
    Qb   = (ushort*)alloc(32 * MB);
    KVb  = (ushort*)alloc(4 * MB);
    Wqb  = (ushort*)alloc(32 * MB);   // Wkvb contiguous after (18432-row B)
    Wkvb = (ushort*)alloc(4 * MB);
    Zb   = (ushort*)alloc(32 * MB);
    VTb  = Wkvb;                 // after QKV-GEMM reads Wkvb
    ZN   = Qb;                   // after attention reads Qb
    h1f  = (float*)Wqb;          // 8 planes x 8 MB = 64 MB over Wqb+Wkvb+Zb[0:28MB]
    H1   = KVb;                  // after attention reads KVb; outside h1f range
    outf = (float*)Qb;           // 4 planes x 4 MB; ZN dead after W1-GEMM
  } else {
    // proven R5 layout (142 MB)
    xn   = (ushort*)alloc(2 * MB);
    Wqb  = (ushort*)alloc(32 * MB);
    Wkvb = (ushort*)alloc(4 * MB);
    W1b  = (ushort*)alloc(64 * MB);
    W2b  = (ushort*)alloc(4 * MB);
    Qb   = (ushort*)alloc(32 * MB);
    KVb  = (ushort*)alloc(4 * MB);
    Zb   = Wqb;
    VTb  = Wkvb;
    ZN   = Qb;
    h1f  = (float*)Wqb;          // 4 planes x 8 MB
    H1   = Wkvb;
    outf = (float*)Qb;
  }

  cvt_all<<<16384 + 2048 + 32768 + 2048, 256, 0, stream>>>(
      Wq_w, Wqb, 16384, Wkv_w, Wkvb, 2048, W1, W1b, 32768, W2, W2b);

  rmsnorm_f32<<<1024, 256, 0, stream>>>(x, gamma_in, xn, 1024, 32.0f);

  // fused Q+KV projection; Q pre-scaled by 1/sqrt(128)
  { dim3 g(8, 144, 1);
    gemm3<2, 0, 1><<<g, 256, 0, stream>>>(xn, Wqb, Wq_b, Wkv_b, Qb, KVb,
                                          1024, 18432, 1024, 1024, 0.08838834764831845f); }

  { dim3 g(16, 8); vtrans<<<g, 256, 0, stream>>>(KVb, VTb); }

  attn9<<<1024, 512, 0, stream>>>(Qb, KVb, VTb, Zb);

  rmsnorm_bf16<<<1024, 256, 0, stream>>>(Zb, gamma_z, ZN, 16384, 128.0f);

  // W1: 8-phase 256^2 split-K=8 when workspace allows; else R5 path
  if (big) {
    dim3 g(4, 8, 8);   // 256 blocks = 1 block/CU (512 thr, 128 KiB LDS)
    gemm8p<<<g, 512, 0, stream>>>(ZN, W1b, h1f, 1024, 2048, 16384, 2048);
    epi_sum_silu<8, 1><<<2048, 256, 0, stream>>>(h1f, b1, H1, 2048, 1024 * 2048 / 4,
                                                 (size_t)1024 * 2048 / 4);
  } else {
    dim3 g(8, 16, 4);
    gemm3<1, 0, 0><<<g, 256, 0, stream>>>(ZN, W1b, b1, nullptr, h1f, nullptr,
                                          1024, 2048, 16384, 4096, 0.f);
    epi_sum_silu<4, 1><<<2048, 256, 0, stream>>>(h1f, b1, H1, 2048, 1024 * 2048 / 4,
                                                 (size_t)1024 * 2048 / 4);
  }

  // W2: split-K=4 planes, then sum+bias+SiLU -> fp32 out
  { dim3 g(8, 8, 4);
    gemm3<1, 0, 0><<<g, 256, 0, stream>>>(H1, W2b, b2, nullptr, outf, nullptr,
                                          1024, 1024, 2048, 512, 0.f); }
  epi_sum_silu<4, 0><<<1024, 256, 0, stream>>>(outf, b2, out, 1024, 1024 * 1024 / 4,
                                               (size_t)1024 * 1024 / 4);
}